// Round 1
// baseline (1204.478 us; speedup 1.0000x reference)
//
#include <hip/hip_runtime.h>

// Problem constants (MyHead_67242007986918)
#define NPTS 80000      // B*NP
#define NPER 20000      // NP per batch
#define CDIM 256
#define NNB  16
#define NKP  15
#define NCLS 17
#define GSH  32
#define GSW  128

typedef __bf16 bf16x8 __attribute__((ext_vector_type(8)));
typedef float  f32x4  __attribute__((ext_vector_type(4)));

__device__ __forceinline__ float bf2f_lo(unsigned int u){ return __uint_as_float(u << 16); }
__device__ __forceinline__ float bf2f_hi(unsigned int u){ return __uint_as_float(u & 0xFFFF0000u); }
__device__ __forceinline__ unsigned short f2bf(float f){
    unsigned int u = __float_as_uint(f);
    u = u + 0x7FFFu + ((u >> 16) & 1u);     // RNE
    return (unsigned short)(u >> 16);
}
__device__ __forceinline__ unsigned int pack2(float a, float b){
    return (unsigned int)f2bf(a) | ((unsigned int)f2bf(b) << 16);
}

// ---------------- ws layout ----------------
// feats  bf16 [NPTS][256]        :      0 .. 40,960,000
// kpwT   bf16 [15][256 d][256 c] : 40,960,000 .. 42,926,080
// outbuf f32  [NPTS][256]        : 42,926,080 .. 124,846,080
// stats  f32  [512] (sum, sumsq) : 124,846,080 .. 124,848,128
#define WS_KPWT   40960000
#define WS_OUT    42926080
#define WS_STATS  124846080
#define WS_NEED   124848128

__global__ void zero_stats_kernel(float* stats){ stats[threadIdx.x] = 0.f; }   // <<<1,512>>>

// Fused rearrange + bilinear grid-sample (border pad, align_corners=False) -> bf16 feats
__global__ __launch_bounds__(256) void gs_kernel(
    const float* __restrict__ x, const float* __restrict__ px,
    const float* __restrict__ py, unsigned short* __restrict__ feats)
{
    int gid = blockIdx.x * 256 + threadIdx.x;           // 80000*64 threads
    int n = gid >> 6;
    if (n >= NPTS) return;
    int c0 = (gid & 63) << 2;
    int b = n / NPER;
    float ix = fminf(fmaxf(((px[n] + 1.f) * (float)GSW - 1.f) * 0.5f, 0.f), (float)(GSW - 1));
    float iy = fminf(fmaxf(((py[n] + 1.f) * (float)GSH - 1.f) * 0.5f, 0.f), (float)(GSH - 1));
    float x0f = floorf(ix), y0f = floorf(iy);
    float wx = ix - x0f, wy = iy - y0f;
    int x0 = (int)x0f, y0 = (int)y0f;
    int x1 = min(x0 + 1, GSW - 1), y1 = min(y0 + 1, GSH - 1);
    const float* base = x + (size_t)b * (GSH * GSW * CDIM);
    float4 v00 = *(const float4*)(base + ((size_t)(y0 * GSW + x0)) * CDIM + c0);
    float4 v01 = *(const float4*)(base + ((size_t)(y0 * GSW + x1)) * CDIM + c0);
    float4 v10 = *(const float4*)(base + ((size_t)(y1 * GSW + x0)) * CDIM + c0);
    float4 v11 = *(const float4*)(base + ((size_t)(y1 * GSW + x1)) * CDIM + c0);
    float w00 = (1.f - wx) * (1.f - wy), w01 = wx * (1.f - wy);
    float w10 = (1.f - wx) * wy,         w11 = wx * wy;
    float r0 = v00.x * w00 + v01.x * w01 + v10.x * w10 + v11.x * w11;
    float r1 = v00.y * w00 + v01.y * w01 + v10.y * w10 + v11.y * w11;
    float r2 = v00.z * w00 + v01.z * w01 + v10.z * w10 + v11.z * w11;
    float r3 = v00.w * w00 + v01.w * w01 + v10.w * w10 + v11.w * w11;
    ushort4 o; o.x = f2bf(r0); o.y = f2bf(r1); o.z = f2bf(r2); o.w = f2bf(r3);
    *(ushort4*)(feats + (size_t)n * CDIM + c0) = o;
}

// kp_weights [k][c][d] f32 -> kpwT [k][d][c] bf16 (so MFMA B-frags read 16B contiguous)
__global__ __launch_bounds__(256) void wt_kernel(
    const float* __restrict__ kpw, unsigned short* __restrict__ kpwT)
{
    int gid = blockIdx.x * 256 + threadIdx.x;           // 15*256*256 = 983040
    int k = gid >> 16;
    int d = (gid >> 8) & 255;
    int c = gid & 255;
    kpwT[gid] = f2bf(kpw[(k << 16) + (c << 8) + d]);
}

// Fused KPConv: w + wf (VALU) + big GEMM (MFMA 16x16x32 bf16) + BN-stat partials.
// Block = 256 thr (4 waves), 64-point tile, full 256 output channels.
__global__ __launch_bounds__(256, 1) void kpconv_kernel(
    const unsigned short* __restrict__ feats,
    const unsigned short* __restrict__ kpwT,
    const int*   __restrict__ pknn,
    const float* __restrict__ pxyz,
    const float* __restrict__ kp_pts,
    float* __restrict__ outbuf,
    float* __restrict__ stats)
{
    __shared__ unsigned short s_fN[16][64][32];   // [a][p][c]  64KB  (phase1 reads contiguous 1KB/wave)
    __shared__ unsigned short s_w [16][64][16];   // [a][p][k]  32KB  (k=15 slot zeroed)
    __shared__ unsigned short s_wf[8][64][40];    // [kk][p][c pad 40] 40KB (pad -> 2-way only, 16B aligned)
    __shared__ int   s_nb[64][16];
    __shared__ float s_kp[NKP][3];

    int tid = threadIdx.x;
    int n0  = blockIdx.x * 64;

    if (tid < NKP * 3) ((float*)s_kp)[tid] = kp_pts[tid];
#pragma unroll
    for (int i = 0; i < 4; i++){
        int r = tid + 256 * i;
        int p = r >> 4, a = r & 15;
        int n = n0 + p;
        int b = n / NPER;                          // blocks may straddle batches
        s_nb[p][a] = b * NPER + pknn[(size_t)n * NNB + a];
    }
    __syncthreads();

    // ---- w[p][a][k] = relu(1 - |dxyz - kp_k| / 1.2), bf16 ----
    {
        int p = tid >> 2, n = n0 + p;
        float cx = pxyz[n * 3 + 0], cy = pxyz[n * 3 + 1], cz = pxyz[n * 3 + 2];
#pragma unroll
        for (int i = 0; i < 4; i++){
            int a = (tid & 3) * 4 + i;
            int g = s_nb[p][a];
            float dx = pxyz[g * 3 + 0] - cx;
            float dy = pxyz[g * 3 + 1] - cy;
            float dz = pxyz[g * 3 + 2] - cz;
#pragma unroll
            for (int k = 0; k < NKP; k++){
                float ex = dx - s_kp[k][0], ey = dy - s_kp[k][1], ez = dz - s_kp[k][2];
                float w = fmaxf(1.f - sqrtf(ex * ex + ey * ey + ez * ez) * (1.f / 1.2f), 0.f);
                s_w[a][p][k] = f2bf(w);
            }
            s_w[a][p][15] = 0;
        }
    }

    f32x4 acc[4][4];
#pragma unroll
    for (int i = 0; i < 4; i++)
#pragma unroll
        for (int j = 0; j < 4; j++){ acc[i][j][0]=0.f; acc[i][j][1]=0.f; acc[i][j][2]=0.f; acc[i][j][3]=0.f; }

    int wv = tid >> 6, lane = tid & 63, m = lane & 15, q = lane >> 4;
    int p1 = tid >> 2, cg = tid & 3;

    for (int ch = 0; ch < 8; ch++){               // 32-channel chunks
        int cbase = ch * 32;
        // ---- stage neighbor features (gather read ONCE per chunk) ----
#pragma unroll
        for (int i = 0; i < 4; i++){
            int r = tid + 256 * i;
            int p = r & 63, a = r >> 6;           // -> contiguous LDS writes across lanes
            const uint4* src = (const uint4*)(feats + (size_t)s_nb[p][a] * CDIM + cbase);
            uint4 v0 = src[0], v1 = src[1], v2 = src[2], v3 = src[3];
            uint4* dst = (uint4*)&s_fN[a][p][0];
            dst[0] = v0; dst[1] = v1; dst[2] = v2; dst[3] = v3;
        }
        __syncthreads();

#pragma unroll
        for (int kg = 0; kg < 2; kg++){           // k groups {0..7}, {8..14}
            const int k0 = kg * 8;
            const int nk = kg ? 7 : 8;
            // ---- phase 1: wf[p][k][c] for this chunk & k-group, in registers ----
            float wf[8][8];
#pragma unroll
            for (int kk = 0; kk < 8; kk++)
#pragma unroll
                for (int c = 0; c < 8; c++) wf[kk][c] = 0.f;
#pragma unroll
            for (int a = 0; a < 16; a++){
                uint4 fv = *(const uint4*)&s_fN[a][p1][cg * 8];
                float fr[8];
                fr[0] = bf2f_lo(fv.x); fr[1] = bf2f_hi(fv.x);
                fr[2] = bf2f_lo(fv.y); fr[3] = bf2f_hi(fv.y);
                fr[4] = bf2f_lo(fv.z); fr[5] = bf2f_hi(fv.z);
                fr[6] = bf2f_lo(fv.w); fr[7] = bf2f_hi(fv.w);
                uint4 wr = *(const uint4*)&s_w[a][p1][k0];
                float wk[8];
                wk[0] = bf2f_lo(wr.x); wk[1] = bf2f_hi(wr.x);
                wk[2] = bf2f_lo(wr.y); wk[3] = bf2f_hi(wr.y);
                wk[4] = bf2f_lo(wr.z); wk[5] = bf2f_hi(wr.z);
                wk[6] = bf2f_lo(wr.w); wk[7] = bf2f_hi(wr.w);
#pragma unroll
                for (int kk = 0; kk < 8; kk++){
                    if (kk >= nk) break;
#pragma unroll
                    for (int c = 0; c < 8; c++)
                        wf[kk][c] = fmaf(wk[kk], fr[c], wf[kk][c]);
                }
            }
#pragma unroll
            for (int kk = 0; kk < 8; kk++){
                if (kk >= nk) break;
                uint4 o;
                o.x = pack2(wf[kk][0], wf[kk][1]);
                o.y = pack2(wf[kk][2], wf[kk][3]);
                o.z = pack2(wf[kk][4], wf[kk][5]);
                o.w = pack2(wf[kk][6], wf[kk][7]);
                *(uint4*)&s_wf[kk][p1][cg * 8] = o;
            }
            __syncthreads();

            // ---- phase 2: MFMA. A[m=lane&15][k=8q+j] (m89/m91 layouts) ----
#pragma unroll
            for (int kk = 0; kk < 8; kk++){
                if (kk >= nk) break;
                int k = k0 + kk;
                bf16x8 A[4];
#pragma unroll
                for (int rt = 0; rt < 4; rt++)
                    A[rt] = *(const bf16x8*)&s_wf[kk][16 * rt + m][8 * q];
#pragma unroll
                for (int ct = 0; ct < 4; ct++){
                    int d = wv * 64 + ct * 16 + m;
                    bf16x8 Bf = *(const bf16x8*)(kpwT + (size_t)k * 65536 + (size_t)d * 256 + cbase + 8 * q);
#pragma unroll
                    for (int rt = 0; rt < 4; rt++)
                        acc[rt][ct] = __builtin_amdgcn_mfma_f32_16x16x32_bf16(A[rt], Bf, acc[rt][ct], 0, 0, 0);
                }
            }
            __syncthreads();
        }
    }

    // ---- epilogue: store fp32, fold BN partial sums via atomics ----
#pragma unroll
    for (int rt = 0; rt < 4; rt++)
#pragma unroll
        for (int ct = 0; ct < 4; ct++)
#pragma unroll
            for (int r = 0; r < 4; r++){
                int prow = 16 * rt + 4 * q + r;          // C/D: row=(lane>>4)*4+r, col=lane&15
                int d = wv * 64 + ct * 16 + m;
                outbuf[(size_t)(n0 + prow) * CDIM + d] = acc[rt][ct][r];
            }
#pragma unroll
    for (int ct = 0; ct < 4; ct++){
        float s1 = 0.f, s2 = 0.f;
#pragma unroll
        for (int rt = 0; rt < 4; rt++)
#pragma unroll
            for (int r = 0; r < 4; r++){
                float v = acc[rt][ct][r];
                s1 += v; s2 += v * v;
            }
        s1 += __shfl_xor(s1, 16); s1 += __shfl_xor(s1, 32);
        s2 += __shfl_xor(s2, 16); s2 += __shfl_xor(s2, 32);
        if (q == 0){
            int d = wv * 64 + ct * 16 + m;
            atomicAdd(&stats[d], s1);
            atomicAdd(&stats[256 + d], s2);
        }
    }
}

// BN (batch stats) + ReLU + 1x1 conv head. 16 points per block.
__global__ __launch_bounds__(256) void head_kernel(
    const float* __restrict__ outbuf, const float* __restrict__ stats,
    const float* __restrict__ gamma,  const float* __restrict__ beta,
    const float* __restrict__ hw,     const float* __restrict__ hb,
    float* __restrict__ logits)
{
    __shared__ float s_h[16][256];
    int tid = threadIdx.x;
    int n0 = blockIdx.x * 16;
    int pt = tid >> 4, cgr = tid & 15;
    {
        int n = n0 + pt;
        const float invN = 1.f / (float)NPTS;
#pragma unroll
        for (int j = 0; j < 16; j += 4){
            int c = cgr * 16 + j;
            float4 v  = *(const float4*)(outbuf + (size_t)n * CDIM + c);
            float4 su = *(const float4*)(stats + c);
            float4 sq = *(const float4*)(stats + 256 + c);
            float4 ga = *(const float4*)(gamma + c);
            float4 be = *(const float4*)(beta + c);
            float mean, var;
            mean = su.x * invN; var = sq.x * invN - mean * mean;
            s_h[pt][c + 0] = fmaxf(ga.x * (v.x - mean) * rsqrtf(var + 1e-5f) + be.x, 0.f);
            mean = su.y * invN; var = sq.y * invN - mean * mean;
            s_h[pt][c + 1] = fmaxf(ga.y * (v.y - mean) * rsqrtf(var + 1e-5f) + be.y, 0.f);
            mean = su.z * invN; var = sq.z * invN - mean * mean;
            s_h[pt][c + 2] = fmaxf(ga.z * (v.z - mean) * rsqrtf(var + 1e-5f) + be.z, 0.f);
            mean = su.w * invN; var = sq.w * invN - mean * mean;
            s_h[pt][c + 3] = fmaxf(ga.w * (v.w - mean) * rsqrtf(var + 1e-5f) + be.w, 0.f);
        }
    }
    __syncthreads();
    for (int idx = tid; idx < 16 * NCLS; idx += 256){
        int pt2 = idx / NCLS, cls = idx - pt2 * NCLS;
        float acc = hb[cls];
#pragma unroll 8
        for (int c = 0; c < CDIM; c += 4){
            float4 h4 = *(const float4*)&s_h[pt2][c];
            float4 w4 = *(const float4*)(hw + (size_t)cls * CDIM + c);
            acc = fmaf(h4.x, w4.x, fmaf(h4.y, w4.y, fmaf(h4.z, w4.z, fmaf(h4.w, w4.w, acc))));
        }
        logits[(size_t)(n0 + pt2) * NCLS + cls] = acc;
    }
}

extern "C" void kernel_launch(void* const* d_in, const int* in_sizes, int n_in,
                              void* d_out, int out_size, void* d_ws, size_t ws_size,
                              hipStream_t stream)
{
    (void)in_sizes; (void)n_in; (void)out_size;
    if (ws_size < (size_t)WS_NEED) return;   // need ~119MB of scratch

    const float* x      = (const float*)d_in[0];
    // d_in[1] = skip  : dead code in reference
    const float* px     = (const float*)d_in[2];
    const float* py     = (const float*)d_in[3];
    const float* pxyz   = (const float*)d_in[4];
    const int*   pknn   = (const int*)  d_in[5];
    // d_in[6] = num_points : unused
    const float* kp_pts = (const float*)d_in[7];
    const float* kpw    = (const float*)d_in[8];
    const float* gamma  = (const float*)d_in[9];
    const float* beta   = (const float*)d_in[10];
    const float* hw     = (const float*)d_in[11];
    const float* hb     = (const float*)d_in[12];
    float* logits = (float*)d_out;

    char* ws = (char*)d_ws;
    unsigned short* feats = (unsigned short*)(ws);
    unsigned short* kpwT  = (unsigned short*)(ws + WS_KPWT);
    float* outbuf = (float*)(ws + WS_OUT);
    float* stats  = (float*)(ws + WS_STATS);

    hipLaunchKernelGGL(zero_stats_kernel, dim3(1),     dim3(512), 0, stream, stats);
    hipLaunchKernelGGL(gs_kernel,         dim3(20000), dim3(256), 0, stream, x, px, py, feats);
    hipLaunchKernelGGL(wt_kernel,         dim3(3840),  dim3(256), 0, stream, kpw, kpwT);
    hipLaunchKernelGGL(kpconv_kernel,     dim3(1250),  dim3(256), 0, stream,
                       feats, kpwT, pknn, pxyz, kp_pts, outbuf, stats);
    hipLaunchKernelGGL(head_kernel,       dim3(5000),  dim3(256), 0, stream,
                       outbuf, stats, gamma, beta, hw, hb, logits);
}

// Round 3
// 951.474 us; speedup vs baseline: 1.2659x; 1.2659x over previous
//
#include <hip/hip_runtime.h>

// Problem constants (MyHead_67242007986918)
#define NPTS 80000      // B*NP
#define NPER 20000      // NP per batch
#define CDIM 256
#define NNB  16
#define NKP  15
#define NCLS 17
#define GSH  32
#define GSW  128

typedef __bf16 bf16x8 __attribute__((ext_vector_type(8)));
typedef float  f32x4  __attribute__((ext_vector_type(4)));
typedef float  f32x2  __attribute__((ext_vector_type(2)));

__device__ __forceinline__ float bf2f_lo(unsigned int u){ return __uint_as_float(u << 16); }
__device__ __forceinline__ float bf2f_hi(unsigned int u){ return __uint_as_float(u & 0xFFFF0000u); }
__device__ __forceinline__ unsigned short f2bf(float f){
    unsigned int u = __float_as_uint(f);
    u = u + 0x7FFFu + ((u >> 16) & 1u);     // RNE
    return (unsigned short)(u >> 16);
}
__device__ __forceinline__ unsigned int pack2(float a, float b){
    return (unsigned int)f2bf(a) | ((unsigned int)f2bf(b) << 16);
}

// ---------------- ws layout (EXACTLY the R1 footprint that fit ws_size) ----------------
// feats  bf16 [NPTS][256]          :      0 .. 40,960,000
// kpwT   bf16 [15][256 d][256 c]   : 40,960,000 .. 42,926,080
// outbuf f32  [NPTS][256]          : 42,926,080 .. 124,846,080
// stats  f32  [512] (sum, sumsq)   : 124,846,080 .. 124,848,128
#define WS_KPWT   40960000
#define WS_OUT    42926080
#define WS_STATS  124846080
#define WS_NEED   124848128

__global__ void zero_stats_kernel(float* stats){ stats[threadIdx.x] = 0.f; }   // <<<1,512>>>

// Fused rearrange + bilinear grid-sample (border pad, align_corners=False) -> bf16 feats
__global__ __launch_bounds__(256) void gs_kernel(
    const float* __restrict__ x, const float* __restrict__ px,
    const float* __restrict__ py, unsigned short* __restrict__ feats)
{
    int gid = blockIdx.x * 256 + threadIdx.x;           // 80000*64 threads
    int n = gid >> 6;
    if (n >= NPTS) return;
    int c0 = (gid & 63) << 2;
    int b = n / NPER;
    float ix = fminf(fmaxf(((px[n] + 1.f) * (float)GSW - 1.f) * 0.5f, 0.f), (float)(GSW - 1));
    float iy = fminf(fmaxf(((py[n] + 1.f) * (float)GSH - 1.f) * 0.5f, 0.f), (float)(GSH - 1));
    float x0f = floorf(ix), y0f = floorf(iy);
    float wx = ix - x0f, wy = iy - y0f;
    int x0 = (int)x0f, y0 = (int)y0f;
    int x1 = min(x0 + 1, GSW - 1), y1 = min(y0 + 1, GSH - 1);
    const float* base = x + (size_t)b * (GSH * GSW * CDIM);
    float4 v00 = *(const float4*)(base + ((size_t)(y0 * GSW + x0)) * CDIM + c0);
    float4 v01 = *(const float4*)(base + ((size_t)(y0 * GSW + x1)) * CDIM + c0);
    float4 v10 = *(const float4*)(base + ((size_t)(y1 * GSW + x0)) * CDIM + c0);
    float4 v11 = *(const float4*)(base + ((size_t)(y1 * GSW + x1)) * CDIM + c0);
    float w00 = (1.f - wx) * (1.f - wy), w01 = wx * (1.f - wy);
    float w10 = (1.f - wx) * wy,         w11 = wx * wy;
    float r0 = v00.x * w00 + v01.x * w01 + v10.x * w10 + v11.x * w11;
    float r1 = v00.y * w00 + v01.y * w01 + v10.y * w10 + v11.y * w11;
    float r2 = v00.z * w00 + v01.z * w01 + v10.z * w10 + v11.z * w11;
    float r3 = v00.w * w00 + v01.w * w01 + v10.w * w10 + v11.w * w11;
    ushort4 o; o.x = f2bf(r0); o.y = f2bf(r1); o.z = f2bf(r2); o.w = f2bf(r3);
    *(ushort4*)(feats + (size_t)n * CDIM + c0) = o;
}

// kp_weights [k][c][d] f32 -> kpwT [15][d][c] bf16.
// gid = (k<<16)|(c<<8)|d -> reads coalesced; writes scatter into L2-resident 2MB buffer.
__global__ __launch_bounds__(256) void wt_kernel(
    const float* __restrict__ kpw, unsigned short* __restrict__ kpwT)
{
    int gid = blockIdx.x * 256 + threadIdx.x;           // 15*65536 = 983,040 -> 3840 blocks
    int k = gid >> 16;
    int c = (gid >> 8) & 255;
    int d = gid & 255;
    kpwT[(k << 16) + (d << 8) + c] = f2bf(kpw[gid]);
}

// Fused KPConv. Block = 256 thr (4 waves), 64-point tile, 256 output channels.
// LDS ~69.8KB -> 2 blocks/CU (8 waves). Chunk = 16 feature channels.
__global__ __launch_bounds__(256, 2) void kpconv_kernel(
    const unsigned short* __restrict__ feats,
    const unsigned short* __restrict__ kpwT,
    const int*   __restrict__ pknn,
    const float* __restrict__ pxyz,
    const float* __restrict__ kp_pts,
    float* __restrict__ outbuf,
    float* __restrict__ stats)
{
    __shared__ unsigned short s_w[2][16][64][8];        // [half][a][p][k8] 32KB, 16B rows -> <=2-way
    __shared__ unsigned short s_wf[8 * 4 * 4 * 16 * 8]; // [pair][rt][q][m][8] 32KB, A-read = lane*16B
    __shared__ int   s_nb[64][16];                      // 4KB
    __shared__ float s_kp[NKP][3];

    int tid = threadIdx.x;
    int n0  = blockIdx.x * 64;

    if (tid < NKP * 3) ((float*)s_kp)[tid] = kp_pts[tid];
#pragma unroll
    for (int i = 0; i < 4; i++){
        int r = tid + 256 * i;
        int p = r >> 4, a = r & 15;
        int n = n0 + p;
        int b = n / NPER;                               // blocks may straddle batches
        s_nb[p][a] = b * NPER + pknn[(size_t)n * NNB + a];
    }
    __syncthreads();

    // ---- w[a][p][k] = relu(1 - |dxyz - kp_k| / 1.2), bf16; k=15 slot zeroed ----
    {
        int p = tid >> 2, n = n0 + p;
        float cx = pxyz[n * 3 + 0], cy = pxyz[n * 3 + 1], cz = pxyz[n * 3 + 2];
#pragma unroll
        for (int i = 0; i < 4; i++){
            int a = (tid & 3) * 4 + i;
            int g = s_nb[p][a];
            float dx = pxyz[g * 3 + 0] - cx;
            float dy = pxyz[g * 3 + 1] - cy;
            float dz = pxyz[g * 3 + 2] - cz;
#pragma unroll
            for (int k = 0; k < NKP; k++){
                float ex = dx - s_kp[k][0], ey = dy - s_kp[k][1], ez = dz - s_kp[k][2];
                float w = fmaxf(1.f - sqrtf(ex * ex + ey * ey + ez * ez) * (1.f / 1.2f), 0.f);
                s_w[k >> 3][a][p][k & 7] = f2bf(w);
            }
            s_w[1][a][p][7] = 0;
        }
    }

    f32x4 acc[4][4];
#pragma unroll
    for (int i = 0; i < 4; i++)
#pragma unroll
        for (int j = 0; j < 4; j++){ acc[i][j][0]=0.f; acc[i][j][1]=0.f; acc[i][j][2]=0.f; acc[i][j][3]=0.f; }

    int wv = tid >> 6, lane = tid & 63, m = lane & 15, q = lane >> 4;
    int p1 = tid >> 2, cg = tid & 3;                    // thread owns point p1, channels cg*4..+3
    int rt1 = p1 >> 4, m1 = p1 & 15;

    // Zero the phantom-k=15 A slots (pair 7, q in {2,3}) ONCE: A=0 x B(any)=0.
    // Each thread writes a distinct uint2; covered slots: [7][rt1][2+(cg>>1)][m1][(cg&1)*4 +0..3].
    {
        int qw = 2 + (cg >> 1);
        int flat = (((7 * 4 + rt1) * 4 + qw) * 16 + m1) * 8 + (cg & 1) * 4;
        *(uint2*)&s_wf[flat] = make_uint2(0u, 0u);
    }
    __syncthreads();

    // hoist neighbor feat offsets (bf16-element offsets, fit in int)
    int foff[16];
#pragma unroll
    for (int a = 0; a < 16; a++) foff[a] = s_nb[p1][a] * CDIM + cg * 4;

    for (int ch = 0; ch < 16; ch++){                    // 16-channel chunks
        int cbase = ch * 16;
        // ---- phase 1: wf[p1][k][4c] for this chunk, packed f32x2 (v_pk_fma) ----
        f32x2 wf[NKP][2];
#pragma unroll
        for (int k = 0; k < NKP; k++){ wf[k][0] = (f32x2)0.f; wf[k][1] = (f32x2)0.f; }
#pragma unroll
        for (int a = 0; a < 16; a++){
            uint2 fv = *(const uint2*)(feats + (size_t)(foff[a] + cbase));   // 4 bf16 gather
            f32x2 fa0; fa0[0] = bf2f_lo(fv.x); fa0[1] = bf2f_hi(fv.x);
            f32x2 fa1; fa1[0] = bf2f_lo(fv.y); fa1[1] = bf2f_hi(fv.y);
            uint4 wlo = *(const uint4*)&s_w[0][a][p1][0];
            uint4 whi = *(const uint4*)&s_w[1][a][p1][0];
            float wk[NKP];
            wk[0]=bf2f_lo(wlo.x); wk[1]=bf2f_hi(wlo.x); wk[2]=bf2f_lo(wlo.y); wk[3]=bf2f_hi(wlo.y);
            wk[4]=bf2f_lo(wlo.z); wk[5]=bf2f_hi(wlo.z); wk[6]=bf2f_lo(wlo.w); wk[7]=bf2f_hi(wlo.w);
            wk[8]=bf2f_lo(whi.x); wk[9]=bf2f_hi(whi.x); wk[10]=bf2f_lo(whi.y); wk[11]=bf2f_hi(whi.y);
            wk[12]=bf2f_lo(whi.z); wk[13]=bf2f_hi(whi.z); wk[14]=bf2f_lo(whi.w);
#pragma unroll
            for (int k = 0; k < NKP; k++){
                f32x2 w2; w2[0] = wk[k]; w2[1] = wk[k];
                wf[k][0] = w2 * fa0 + wf[k][0];
                wf[k][1] = w2 * fa1 + wf[k][1];
            }
        }
        // ---- write wf -> s_wf in MFMA-A layout [pair][rt][q][m][8] ----
        // (pair = k>>1, q-slot = (k&1)*2 + (cg>>1), channel-within-8 = 4*(cg&1)+i)
#pragma unroll
        for (int k = 0; k < NKP; k++){
            uint2 o;
            o.x = pack2(wf[k][0][0], wf[k][0][1]);
            o.y = pack2(wf[k][1][0], wf[k][1][1]);
            int qw = (k & 1) * 2 + (cg >> 1);
            int flat = (((((k >> 1) * 4 + rt1) * 4 + qw) * 16) + m1) * 8 + (cg & 1) * 4;
            *(uint2*)&s_wf[flat] = o;
        }
        __syncthreads();

        // ---- phase 2: MFMA 16x16x32 bf16. K-window = k-pair x 16 channels ----
#pragma unroll
        for (int w8 = 0; w8 < 8; w8++){
            bf16x8 A[4];
#pragma unroll
            for (int rt = 0; rt < 4; rt++)
                A[rt] = *(const bf16x8*)&s_wf[((((w8 * 4 + rt) * 4 + q) * 16) + m) * 8];
            int k = 2 * w8 + (q >> 1);                  // k==15 lanes: A==0, clamp B ptr
            int keff = (k < NKP) ? k : 0;
            const unsigned short* bbase = kpwT + ((size_t)keff << 16) + cbase + (q & 1) * 8;
#pragma unroll
            for (int ct = 0; ct < 4; ct++){
                int d = wv * 64 + ct * 16 + m;
                bf16x8 Bf = *(const bf16x8*)(bbase + d * 256);
#pragma unroll
                for (int rt = 0; rt < 4; rt++)
                    acc[rt][ct] = __builtin_amdgcn_mfma_f32_16x16x32_bf16(A[rt], Bf, acc[rt][ct], 0, 0, 0);
            }
        }
        __syncthreads();
    }

    // ---- epilogue: store fp32, fold BN partial sums via atomics ----
#pragma unroll
    for (int rt = 0; rt < 4; rt++)
#pragma unroll
        for (int ct = 0; ct < 4; ct++)
#pragma unroll
            for (int r = 0; r < 4; r++){
                int prow = 16 * rt + 4 * q + r;         // C/D: row=(lane>>4)*4+r, col=lane&15
                int d = wv * 64 + ct * 16 + m;
                outbuf[(size_t)(n0 + prow) * CDIM + d] = acc[rt][ct][r];
            }
#pragma unroll
    for (int ct = 0; ct < 4; ct++){
        float s1 = 0.f, s2 = 0.f;
#pragma unroll
        for (int rt = 0; rt < 4; rt++)
#pragma unroll
            for (int r = 0; r < 4; r++){
                float v = acc[rt][ct][r];
                s1 += v; s2 += v * v;
            }
        s1 += __shfl_xor(s1, 16); s1 += __shfl_xor(s1, 32);
        s2 += __shfl_xor(s2, 16); s2 += __shfl_xor(s2, 32);
        if (q == 0){
            int d = wv * 64 + ct * 16 + m;
            atomicAdd(&stats[d], s1);
            atomicAdd(&stats[256 + d], s2);
        }
    }
}

// BN (batch stats) + ReLU + 1x1 conv head. 16 points per block.
__global__ __launch_bounds__(256) void head_kernel(
    const float* __restrict__ outbuf, const float* __restrict__ stats,
    const float* __restrict__ gamma,  const float* __restrict__ beta,
    const float* __restrict__ hw,     const float* __restrict__ hb,
    float* __restrict__ logits)
{
    __shared__ float s_h[16][256];
    int tid = threadIdx.x;
    int n0 = blockIdx.x * 16;
    int pt = tid >> 4, cgr = tid & 15;
    {
        int n = n0 + pt;
        const float invN = 1.f / (float)NPTS;
#pragma unroll
        for (int j = 0; j < 16; j += 4){
            int c = cgr * 16 + j;
            float4 v  = *(const float4*)(outbuf + (size_t)n * CDIM + c);
            float4 su = *(const float4*)(stats + c);
            float4 sq = *(const float4*)(stats + 256 + c);
            float4 ga = *(const float4*)(gamma + c);
            float4 be = *(const float4*)(beta + c);
            float mean, var;
            mean = su.x * invN; var = sq.x * invN - mean * mean;
            s_h[pt][c + 0] = fmaxf(ga.x * (v.x - mean) * rsqrtf(var + 1e-5f) + be.x, 0.f);
            mean = su.y * invN; var = sq.y * invN - mean * mean;
            s_h[pt][c + 1] = fmaxf(ga.y * (v.y - mean) * rsqrtf(var + 1e-5f) + be.y, 0.f);
            mean = su.z * invN; var = sq.z * invN - mean * mean;
            s_h[pt][c + 2] = fmaxf(ga.z * (v.z - mean) * rsqrtf(var + 1e-5f) + be.z, 0.f);
            mean = su.w * invN; var = sq.w * invN - mean * mean;
            s_h[pt][c + 3] = fmaxf(ga.w * (v.w - mean) * rsqrtf(var + 1e-5f) + be.w, 0.f);
        }
    }
    __syncthreads();
    for (int idx = tid; idx < 16 * NCLS; idx += 256){
        int pt2 = idx / NCLS, cls = idx - pt2 * NCLS;
        float acc = hb[cls];
#pragma unroll 8
        for (int c = 0; c < CDIM; c += 4){
            float4 h4 = *(const float4*)&s_h[pt2][c];
            float4 w4 = *(const float4*)(hw + (size_t)cls * CDIM + c);
            acc = fmaf(h4.x, w4.x, fmaf(h4.y, w4.y, fmaf(h4.z, w4.z, fmaf(h4.w, w4.w, acc))));
        }
        logits[(size_t)(n0 + pt2) * NCLS + cls] = acc;
    }
}

extern "C" void kernel_launch(void* const* d_in, const int* in_sizes, int n_in,
                              void* d_out, int out_size, void* d_ws, size_t ws_size,
                              hipStream_t stream)
{
    (void)in_sizes; (void)n_in; (void)out_size;
    if (ws_size < (size_t)WS_NEED) return;   // R1-verified footprint (119.06 MB)

    const float* x      = (const float*)d_in[0];
    // d_in[1] = skip  : dead code in reference
    const float* px     = (const float*)d_in[2];
    const float* py     = (const float*)d_in[3];
    const float* pxyz   = (const float*)d_in[4];
    const int*   pknn   = (const int*)  d_in[5];
    // d_in[6] = num_points : unused
    const float* kp_pts = (const float*)d_in[7];
    const float* kpw    = (const float*)d_in[8];
    const float* gamma  = (const float*)d_in[9];
    const float* beta   = (const float*)d_in[10];
    const float* hw     = (const float*)d_in[11];
    const float* hb     = (const float*)d_in[12];
    float* logits = (float*)d_out;

    char* ws = (char*)d_ws;
    unsigned short* feats = (unsigned short*)(ws);
    unsigned short* kpwT  = (unsigned short*)(ws + WS_KPWT);
    float* outbuf = (float*)(ws + WS_OUT);
    float* stats  = (float*)(ws + WS_STATS);

    hipLaunchKernelGGL(zero_stats_kernel, dim3(1),     dim3(512), 0, stream, stats);
    hipLaunchKernelGGL(gs_kernel,         dim3(20000), dim3(256), 0, stream, x, px, py, feats);
    hipLaunchKernelGGL(wt_kernel,         dim3(3840),  dim3(256), 0, stream, kpw, kpwT);
    hipLaunchKernelGGL(kpconv_kernel,     dim3(1250),  dim3(256), 0, stream,
                       feats, kpwT, pknn, pxyz, kp_pts, outbuf, stats);
    hipLaunchKernelGGL(head_kernel,       dim3(5000),  dim3(256), 0, stream,
                       outbuf, stats, gamma, beta, hw, hb, logits);
}